// Round 17
// baseline (446.631 us; speedup 1.0000x reference)
//
#include <hip/hip_runtime.h>
#include <hip/hip_bf16.h>
#include <type_traits>

#define NN 100000
#define NE 1600000
// IN_CH=500, HID=128, OUT_CH=40

#define SCAN_E 1024
#define NBLK ((NN + SCAN_E - 1) / SCAN_E)  // 98
#define GBLK ((NN + 127) / 128)            // 782 gemm blocks (128 rows each)
#define FBLK (NN / 16)                     // 6250 fused pull blocks (16 nodes each)
#define PSZ 12500                          // dst-partition size (8 * 12500 = NN)
#define CSZ 50000                          // edge-chunk size (32 * 50000 = NE)
#define NCH 32                             // chunks
#define HBLK 256                           // hist blocks = 8 partitions * 32 chunks

using f32x4 = __attribute__((ext_vector_type(4))) float;
using bf16x8 = __attribute__((ext_vector_type(8))) short;  // 8 bf16 in 4 VGPRs
using u16 = unsigned short;
using u32 = unsigned int;
using u64 = unsigned long long;

__device__ inline u16 f2bf(float f) {
    unsigned u = __float_as_uint(f);
    unsigned r = (u + 0x7fffu + ((u >> 16) & 1u)) >> 16;  // RNE
    return (u16)r;
}
__device__ inline float bflo(unsigned u) { return __uint_as_float(u << 16); }
__device__ inline float bfhi(unsigned u) { return __uint_as_float(u & 0xffff0000u); }
__device__ inline float bf2f(u16 u) { return __uint_as_float((unsigned)u << 16); }
// packed fp32x2 -> bf16x2 (RNE); lowers to v_cvt_pk_bf16_f32 on gfx950
__device__ inline unsigned cvt2(float a, float b) {
    union { __hip_bfloat162 h; unsigned u; } c;
    c.h = __float22bfloat162_rn(make_float2(a, b));
    return c.u;
}

// ---------------- MFMA GEMM1 body: fp32 A, software-pipelined X stream ----------------
// 1-deep prefetch: load kstep ks+1 before the cvt+MFMA chain of ks, so each wave
// keeps ~2 loads in flight (vs ~1 with the naive loop) — K1 was latency-bound at
// 1.4 TB/s aggregate. Out-of-range rows are CLAMPED (not branched): garbage A rows
// only feed output rows that are never stored; k>=KLIM cols are zero in packed W.
template <int KLIM, int KSTEPS>
__device__ __forceinline__ void gemm1_body(const float* __restrict__ X,
                                           const short* __restrict__ Wp,
                                           u16* __restrict__ Out, int gblk) {
    const int lane = threadIdx.x & 63;
    const int wave = threadIdx.x >> 6;
    const int row0 = gblk * 128 + wave * 16;
    const int arow0 = row0 + (lane & 15);
    const int kgrp = (lane >> 4) << 3;
    const int arow = (arow0 < NN) ? arow0 : (NN - 1);  // clamp: safe garbage
    const float* aptr = X + (size_t)arow * KLIM + kgrp;
    const bf16x8* wp = reinterpret_cast<const bf16x8*>(Wp);

    f32x4 acc[8];
#pragma unroll
    for (int nt = 0; nt < 8; nt++) acc[nt] = (f32x4){0.f, 0.f, 0.f, 0.f};

    const int FULL = KSTEPS - 1;  // last kstep has the k<KLIM tail guard
    f32x4 c0 = *reinterpret_cast<const f32x4*>(aptr);
    f32x4 c1 = *reinterpret_cast<const f32x4*>(aptr + 4);
#pragma unroll
    for (int ks = 0; ks < FULL; ks++) {
        const int kp = (ks + 1 < FULL) ? ks + 1 : FULL - 1;  // clamped prefetch
        f32x4 n0 = *reinterpret_cast<const f32x4*>(aptr + kp * 32);
        f32x4 n1 = *reinterpret_cast<const f32x4*>(aptr + kp * 32 + 4);
        union { bf16x8 v; unsigned u[4]; } a;
        a.u[0] = cvt2(c0.x, c0.y);
        a.u[1] = cvt2(c0.z, c0.w);
        a.u[2] = cvt2(c1.x, c1.y);
        a.u[3] = cvt2(c1.z, c1.w);
#pragma unroll
        for (int nt = 0; nt < 8; nt++) {
            bf16x8 bf = wp[(ks * 8 + nt) * 64 + lane];
            acc[nt] = __builtin_amdgcn_mfma_f32_16x16x32_bf16(a.v, bf, acc[nt], 0, 0, 0);
        }
        c0 = n0;
        c1 = n1;
    }
    {  // tail kstep (guarded element loads; W rows k>=KLIM are zero anyway)
        const int ks = KSTEPS - 1;
        bf16x8 af;
#pragma unroll
        for (int j = 0; j < 8; j++) {
            int k = ks * 32 + kgrp + j;
            af[j] = (k < KLIM) ? (short)f2bf(aptr[ks * 32 + j]) : (short)0;
        }
#pragma unroll
        for (int nt = 0; nt < 8; nt++) {
            bf16x8 bf = wp[(ks * 8 + nt) * 64 + lane];
            acc[nt] = __builtin_amdgcn_mfma_f32_16x16x32_bf16(af, bf, acc[nt], 0, 0, 0);
        }
    }

    const int rbase = row0 + ((lane >> 4) << 2);
    const int cbase = lane & 15;
#pragma unroll
    for (int r = 0; r < 4; r++) {
        int orow = rbase + r;
        if (orow < NN) {
            u16* p = Out + (size_t)orow * 128 + cbase;
#pragma unroll
            for (int nt = 0; nt < 8; nt += 2) {
                unsigned v = cvt2(acc[nt][r], acc[nt + 1][r]);
                p[nt * 16] = (u16)v;
                p[nt * 16 + 16] = (u16)(v >> 16);
            }
        }
    }
}

// ---------------- K1: LDS-histogram count/rank (blocks < HBLK) + GEMM1 ----------------
// Block (p,c): LDS histogram of packed (count<<24 | fxsum(ea*2^15)) for dsts in
// partition p (12500 nodes, 50 KB) over edge chunk c (50000 edges).
// old>>24 = local rank within (c,d). counts[c][d] written with plain stores.
__global__ __launch_bounds__(512) void k_hist_gemm1(const float* __restrict__ X,
                                                    const short* __restrict__ Wp,
                                                    u16* __restrict__ Out,
                                                    const int* __restrict__ ei,
                                                    const float* __restrict__ ea,
                                                    u32* __restrict__ counts,
                                                    int* __restrict__ rank) {
    __shared__ u32 hist[PSZ];
    if (blockIdx.x < HBLK) {
        const int p = blockIdx.x >> 5;
        const int c = blockIdx.x & 31;
        const int dbase = p * PSZ;
        for (int i = threadIdx.x; i < PSZ; i += 512) hist[i] = 0;
        __syncthreads();
        const int ebeg = c * CSZ;
#pragma unroll 2
        for (int e = ebeg + (int)threadIdx.x; e < ebeg + CSZ; e += 512) {
            int d = ei[NE + e];
            unsigned rel = (unsigned)(d - dbase);
            if (rel < PSZ) {
                float w = ea[e];  // load only on partition hit (~1/8 of lanes)
                u32 add = (1u << 24) | (u32)(w * 32768.0f);
                u32 old = atomicAdd(&hist[rel], add);
                rank[e] = (int)(old >> 24);
            }
        }
        __syncthreads();
        for (int i = threadIdx.x; i < PSZ; i += 512)
            counts[(size_t)c * NN + dbase + i] = hist[i];
        return;
    }
    gemm1_body<500, 16>(X, Wp, Out, blockIdx.x - HBLK);
}

// ---------------- scan: fold 32 chunks per node (+cpfx, +dinv) ----------------
__global__ __launch_bounds__(256) void k_scan1(const u32* __restrict__ counts,
                                               u16* __restrict__ cpfx,
                                               int* __restrict__ row_ptr,
                                               int* __restrict__ part,
                                               float* __restrict__ dinv) {
    __shared__ int ts[256];
    const int tid = threadIdx.x;
    int base = blockIdx.x * SCAN_E + tid * 4;
    int v[4];
    int ssum = 0;
#pragma unroll
    for (int j = 0; j < 4; j++) {
        int d = base + j;
        if (d < NN) {
            u32 acc = 0;
#pragma unroll
            for (int c = 0; c < NCH; c++) {
                cpfx[(size_t)c * NN + d] = (u16)(acc >> 24);
                acc += counts[(size_t)c * NN + d];
            }
            v[j] = (int)(acc >> 24);
            dinv[d] = rsqrtf((float)(acc & 0xFFFFFFu) * (1.0f / 32768.0f) + 1.0f);
        } else {
            v[j] = 0;
        }
        ssum += v[j];
    }
    ts[tid] = ssum;
    __syncthreads();
    for (int o = 1; o < 256; o <<= 1) {
        int t = (tid >= o) ? ts[tid - o] : 0;
        __syncthreads();
        ts[tid] += t;
        __syncthreads();
    }
    int excl = ts[tid] - ssum;
#pragma unroll
    for (int j = 0; j < 4; j++) {
        if (base + j < NN) row_ptr[base + j] = excl;
        excl += v[j];
    }
    if (tid == 255) part[blockIdx.x] = ts[255];
}

__global__ void k_scan2(int* __restrict__ part) {
    if (threadIdx.x == 0) {
        int acc = 0;
        for (int b = 0; b < NBLK; b++) { int t = part[b]; part[b] = acc; acc += t; }
    }
}

__global__ __launch_bounds__(256) void k_scan3(int* __restrict__ row_ptr,
                                               const int* __restrict__ part) {
    int base = blockIdx.x * SCAN_E + threadIdx.x * 4;
    int off = part[blockIdx.x];
#pragma unroll
    for (int j = 0; j < 4; j++)
        if (base + j < NN) row_ptr[base + j] += off;
    if (blockIdx.x == 0 && threadIdx.x == 0) row_ptr[NN] = NE;
}

// ---------------- atomic-free scatter: pos = row_ptr[d] + cpfx[c][d] + rank[e] ----------------
__global__ __launch_bounds__(256) void k_scatter(const int* __restrict__ ei,
                                                 const float* __restrict__ ea,
                                                 const float* __restrict__ dinv,
                                                 const int* __restrict__ row_ptr,
                                                 const u16* __restrict__ cpfx,
                                                 const int* __restrict__ rank,
                                                 int2* __restrict__ csr) {
    int e = blockIdx.x * 256 + threadIdx.x;
    if (e >= NE) return;
    int s = ei[e], d = ei[NE + e];
    int c = e / CSZ;
    int pos = row_ptr[d] + (int)cpfx[(size_t)c * NN + d] + rank[e];
    float w = dinv[s] * ea[e] * dinv[d];
    csr[pos] = make_int2(s, __float_as_int(w));
}

// ---------------- single W-pack kernel (W1 | W2 | W3) ----------------
__device__ __forceinline__ void pack128(const float* __restrict__ W,
                                        short* __restrict__ Wp, int K, int t) {
    int lane = t & 63;
    int nt = (t >> 6) & 7;
    int ks = t >> 9;
    int col = nt * 16 + (lane & 15);
    int kb = ks * 32 + ((lane >> 4) << 3);
    bf16x8 v;
#pragma unroll
    for (int j = 0; j < 8; j++) {
        int k = kb + j;
        v[j] = (k < K) ? (short)f2bf(W[(size_t)k * 128 + col]) : (short)0;
    }
    reinterpret_cast<bf16x8*>(Wp)[t] = v;
}

__global__ __launch_bounds__(256) void k_packAll(const float* __restrict__ W1,
                                                 const float* __restrict__ W2,
                                                 const float* __restrict__ W3,
                                                 short* __restrict__ Wp1,
                                                 short* __restrict__ Wp2,
                                                 short* __restrict__ Wp3) {
    int t = blockIdx.x * 256 + threadIdx.x;
    if (t < 8192) {
        pack128(W1, Wp1, 500, t);
    } else if (t < 10240) {
        pack128(W2, Wp2, 128, t - 8192);
    } else if (t < 11008) {
        int tt = t - 10240;  // W3 [128][40] -> 3 n-tiles (48 cols, padded), 4 ksteps
        int lane = tt & 63;
        int nt = (tt >> 6) % 3;
        int ks = tt / 192;
        int col = nt * 16 + (lane & 15);
        int kb = ks * 32 + ((lane >> 4) << 3);
        bf16x8 v;
#pragma unroll
        for (int j = 0; j < 8; j++)
            v[j] = (col < 40) ? (short)f2bf(W3[(size_t)(kb + j) * 40 + col]) : (short)0;
        reinterpret_cast<bf16x8*>(Wp3)[tt] = v;
    }
}

// ---------------- fused CSR pull + dense transform ----------------
// 512 threads, 16 nodes/block (32 lanes/node). Phase 1: cooperative pull into
// LDS tile (padded). Phase 2: tile @ Wg via MFMA.
// MODE 1: h1 = relu(acc+b1) -> OutRow + tile@W2 -> OutG (8 n-tiles).
// MODE 2: h2 = relu(acc+b2)+R (LDS only); tile@W3 -> OutG stride-64 (3 n-tiles).
template <int MODE>
__global__ __launch_bounds__(512) void k_pull_fused(const u16* __restrict__ H,
                                                    const int* __restrict__ row_ptr,
                                                    const int2* __restrict__ csr,
                                                    const float* __restrict__ dinv,
                                                    const float* __restrict__ b,
                                                    const u16* __restrict__ R,
                                                    u16* __restrict__ OutRow,
                                                    const short* __restrict__ Wg,
                                                    u16* __restrict__ OutG) {
    __shared__ u16 tile[16][136];
    const int nl = threadIdx.x >> 5;          // 0..15 node-local
    const int node = blockIdx.x * 16 + nl;    // FBLK*16 == NN exactly
    const int cg = threadIdx.x & 31;
    const uint2* H2v = reinterpret_cast<const uint2*>(H);  // row stride 32

    float dv = dinv[node];
    float sw = dv * dv;  // self-loop weight
    uint2 h = H2v[node * 32 + cg];
    float4 acc;
    acc.x = bflo(h.x) * sw; acc.y = bfhi(h.x) * sw;
    acc.z = bflo(h.y) * sw; acc.w = bfhi(h.y) * sw;

    int e0 = row_ptr[node], e1 = row_ptr[node + 1];
    for (int base = e0; base < e1; base += 32) {
        int n = e1 - base;
        if (n > 32) n = 32;
        int2 sv = (cg < n) ? csr[base + cg] : make_int2(0, 0);
        int j = 0;
        for (; j + 4 <= n; j += 4) {
            int s0 = __shfl(sv.x, j + 0, 32);
            int s1 = __shfl(sv.x, j + 1, 32);
            int s2 = __shfl(sv.x, j + 2, 32);
            int s3 = __shfl(sv.x, j + 3, 32);
            float w0 = __int_as_float(__shfl(sv.y, j + 0, 32));
            float w1 = __int_as_float(__shfl(sv.y, j + 1, 32));
            float w2 = __int_as_float(__shfl(sv.y, j + 2, 32));
            float w3 = __int_as_float(__shfl(sv.y, j + 3, 32));
            uint2 g0 = H2v[s0 * 32 + cg];
            uint2 g1 = H2v[s1 * 32 + cg];
            uint2 g2 = H2v[s2 * 32 + cg];
            uint2 g3 = H2v[s3 * 32 + cg];
            acc.x = fmaf(w0, bflo(g0.x), acc.x); acc.y = fmaf(w0, bfhi(g0.x), acc.y);
            acc.z = fmaf(w0, bflo(g0.y), acc.z); acc.w = fmaf(w0, bfhi(g0.y), acc.w);
            acc.x = fmaf(w1, bflo(g1.x), acc.x); acc.y = fmaf(w1, bfhi(g1.x), acc.y);
            acc.z = fmaf(w1, bflo(g1.y), acc.z); acc.w = fmaf(w1, bfhi(g1.y), acc.w);
            acc.x = fmaf(w2, bflo(g2.x), acc.x); acc.y = fmaf(w2, bfhi(g2.x), acc.y);
            acc.z = fmaf(w2, bflo(g2.y), acc.z); acc.w = fmaf(w2, bfhi(g2.y), acc.w);
            acc.x = fmaf(w3, bflo(g3.x), acc.x); acc.y = fmaf(w3, bfhi(g3.x), acc.y);
            acc.z = fmaf(w3, bflo(g3.y), acc.z); acc.w = fmaf(w3, bfhi(g3.y), acc.w);
        }
        for (; j < n; j++) {
            int s = __shfl(sv.x, j, 32);
            float w = __int_as_float(__shfl(sv.y, j, 32));
            uint2 g = H2v[s * 32 + cg];
            acc.x = fmaf(w, bflo(g.x), acc.x); acc.y = fmaf(w, bfhi(g.x), acc.y);
            acc.z = fmaf(w, bflo(g.y), acc.z); acc.w = fmaf(w, bfhi(g.y), acc.w);
        }
    }

    float4 bb = reinterpret_cast<const float4*>(b)[cg];
    float4 o;
    o.x = fmaxf(acc.x + bb.x, 0.f);
    o.y = fmaxf(acc.y + bb.y, 0.f);
    o.z = fmaxf(acc.z + bb.z, 0.f);
    o.w = fmaxf(acc.w + bb.w, 0.f);
    if (MODE == 2) {
        uint2 r = reinterpret_cast<const uint2*>(R)[node * 32 + cg];
        o.x += bflo(r.x); o.y += bfhi(r.x);
        o.z += bflo(r.y); o.w += bfhi(r.y);
    }
    uint2 pk = make_uint2(cvt2(o.x, o.y), cvt2(o.z, o.w));
    *reinterpret_cast<uint2*>(&tile[nl][cg * 4]) = pk;
    if (MODE == 1)
        reinterpret_cast<uint2*>(OutRow)[node * 32 + cg] = pk;  // h1 for residual

    __syncthreads();

    // ---- gemm phase: tile(16x128) @ Wg ----
    const int lane = threadIdx.x & 63;
    const int wave = threadIdx.x >> 6;  // 0..7
    const int NT = (MODE == 1) ? 8 : 3;
    if (wave < NT) {
        const bf16x8* wp = reinterpret_cast<const bf16x8*>(Wg);
        f32x4 gacc = (f32x4){0.f, 0.f, 0.f, 0.f};
        const int arow = lane & 15;
        const int kg = (lane >> 4) << 3;
#pragma unroll
        for (int ks = 0; ks < 4; ks++) {
            bf16x8 af = *reinterpret_cast<const bf16x8*>(&tile[arow][ks * 32 + kg]);
            bf16x8 bf = wp[(ks * NT + wave) * 64 + lane];
            gacc = __builtin_amdgcn_mfma_f32_16x16x32_bf16(af, bf, gacc, 0, 0, 0);
        }
        const int rb = ((lane >> 4) << 2);
        const int cb = lane & 15;
        if (MODE == 1) {
            u16* p = OutG + (size_t)(blockIdx.x * 16 + rb) * 128 + wave * 16 + cb;
#pragma unroll
            for (int r = 0; r < 4; r++) p[(size_t)r * 128] = f2bf(gacc[r]);
        } else {
            int col = wave * 16 + cb;
            if (col < 40) {
                u16* p = OutG + (size_t)(blockIdx.x * 16 + rb) * 64 + col;
#pragma unroll
                for (int r = 0; r < 4; r++) p[(size_t)r * 64] = f2bf(gacc[r]);
            }
        }
    }
}

// ---------------- layer 3: pull(40ch, stride-64 bf16) + bias + log_softmax ----------------
__global__ __launch_bounds__(256) void k_pull40_lsm(const u16* __restrict__ G,
                                                    const int* __restrict__ row_ptr,
                                                    const int2* __restrict__ csr,
                                                    const float* __restrict__ dinv,
                                                    const float* __restrict__ b3,
                                                    float* __restrict__ out) {
    int node = blockIdx.x * 4 + (threadIdx.x >> 6);
    int lane = threadIdx.x & 63;
    const bool act = lane < 40;
    float dv = dinv[node];
    float sw = dv * dv;
    float acc = act ? bf2f(G[node * 64 + lane]) * sw : 0.f;

    int e0 = row_ptr[node], e1 = row_ptr[node + 1];
    for (int base = e0; base < e1; base += 64) {
        int n = e1 - base;
        if (n > 64) n = 64;
        int2 sv = (lane < n) ? csr[base + lane] : make_int2(0, 0);
        int j = 0;
        for (; j + 4 <= n; j += 4) {
            int s0 = __shfl(sv.x, j + 0);
            int s1 = __shfl(sv.x, j + 1);
            int s2 = __shfl(sv.x, j + 2);
            int s3 = __shfl(sv.x, j + 3);
            float w0 = __int_as_float(__shfl(sv.y, j + 0));
            float w1 = __int_as_float(__shfl(sv.y, j + 1));
            float w2 = __int_as_float(__shfl(sv.y, j + 2));
            float w3 = __int_as_float(__shfl(sv.y, j + 3));
            float g0 = act ? bf2f(G[s0 * 64 + lane]) : 0.f;
            float g1 = act ? bf2f(G[s1 * 64 + lane]) : 0.f;
            float g2 = act ? bf2f(G[s2 * 64 + lane]) : 0.f;
            float g3 = act ? bf2f(G[s3 * 64 + lane]) : 0.f;
            acc = fmaf(w0, g0, acc);
            acc = fmaf(w1, g1, acc);
            acc = fmaf(w2, g2, acc);
            acc = fmaf(w3, g3, acc);
        }
        for (; j < n; j++) {
            int s = __shfl(sv.x, j);
            float w = __int_as_float(__shfl(sv.y, j));
            float g = act ? bf2f(G[s * 64 + lane]) : 0.f;
            acc = fmaf(w, g, acc);
        }
    }

    float v = act ? acc + b3[lane] : -1e30f;
    float m = v;
    for (int o = 32; o; o >>= 1) m = fmaxf(m, __shfl_xor(m, o));
    float e = act ? expf(v - m) : 0.f;
    float ssum = e;
    for (int o = 32; o; o >>= 1) ssum += __shfl_xor(ssum, o);
    float ls = logf(ssum);
    if (act) out[node * 40 + lane] = v - m - ls;
}

// ---------------- launch ----------------
extern "C" void kernel_launch(void* const* d_in, const int* in_sizes, int n_in,
                              void* d_out, int out_size, void* d_ws, size_t ws_size,
                              hipStream_t stream) {
    const float* x  = (const float*)d_in[0];
    const int*   ei = (const int*)d_in[1];   // [2, NE] int32
    const float* ea = (const float*)d_in[2];
    const float* W1 = (const float*)d_in[3];
    const float* b1 = (const float*)d_in[4];
    const float* W2 = (const float*)d_in[5];
    const float* b2 = (const float*)d_in[6];
    const float* W3 = (const float*)d_in[7];
    const float* b3 = (const float*)d_in[8];
    float* out = (float*)d_out;

    // workspace carve-up (all regions 16 B aligned)
    short* Wp1     = (short*)d_ws;                    // 65536 bf16 (128 KB)
    short* Wp2     = Wp1 + 65536;                     // 16384 bf16 (32 KB)
    short* Wp3     = Wp2 + 16384;                     // 6144 bf16 (12 KB)
    u16*   Hb      = (u16*)(Wp3 + 6144);              // NN*128 bf16 (X@W1)
    u16*   h1b     = Hb + (size_t)NN * 128;           // NN*128 bf16 (h1)
    u16*   H2     = h1b + (size_t)NN * 128;           // NN*128 bf16 (h1@W2)
    u16*   G3b     = H2 + (size_t)NN * 128;           // NN*64 bf16 (padded rows)
    float* dinv    = (float*)(G3b + (size_t)NN * 64); // NN f32
    int*   row_ptr = (int*)(dinv + NN);               // NN+1 (pad 8)
    int*   part    = row_ptr + NN + 8;                // NBLK (pad 128)
    int*   rank    = part + 128;                      // NE i32
    u32*   counts  = (u32*)(rank + NE);               // 32*NN u32 (12.8 MB)
    u16*   cpfx    = (u16*)(counts + (size_t)NCH * NN); // 32*NN u16 (6.4 MB)
    int2*  csr     = (int2*)(cpfx + (size_t)NCH * NN); // NE int2

    // ---- W packing (single launch)
    k_packAll<<<43, 256, 0, stream>>>(W1, W2, W3, Wp1, Wp2, Wp3);

    // ---- K1: LDS-hist count/rank (256 blocks) || Hb = X @ W1 (782 blocks)
    k_hist_gemm1<<<HBLK + GBLK, 512, 0, stream>>>(x, Wp1, Hb, ei, ea, counts, rank);

    // ---- scan: fold chunks (+cpfx, +dinv), then row_ptr prefix
    k_scan1<<<NBLK, 256, 0, stream>>>(counts, cpfx, row_ptr, part, dinv);
    k_scan2<<<1, 64, 0, stream>>>(part);
    k_scan3<<<NBLK, 256, 0, stream>>>(row_ptr, part);

    // ---- atomic-free scatter
    k_scatter<<<(NE + 255) / 256, 256, 0, stream>>>(ei, ea, dinv, row_ptr, cpfx,
                                                    rank, csr);

    // ---- fused layer1-agg + layer2-lin: h1b = relu(pull(Hb)+b1); H2 = h1 @ W2
    k_pull_fused<1><<<FBLK, 512, 0, stream>>>(Hb, row_ptr, csr, dinv, b1, nullptr,
                                              h1b, Wp2, H2);

    // ---- fused layer2-agg + layer3-lin: h2 = relu(pull(H2)+b2)+h1 (LDS only);
    //      G3b = h2 @ W3 (stride-64)
    k_pull_fused<2><<<FBLK, 512, 0, stream>>>(H2, row_ptr, csr, dinv, b2, h1b,
                                              nullptr, Wp3, G3b);

    // ---- layer 3 agg + log_softmax
    k_pull40_lsm<<<NN / 4, 256, 0, stream>>>(G3b, row_ptr, csr, dinv, b3, out);
}

// Round 18
// 425.295 us; speedup vs baseline: 1.0502x; 1.0502x over previous
//
#include <hip/hip_runtime.h>
#include <hip/hip_bf16.h>
#include <type_traits>

#define NN 100000
#define NE 1600000
// IN_CH=500, HID=128, OUT_CH=40

#define SCAN_E 1024
#define NBLK ((NN + SCAN_E - 1) / SCAN_E)  // 98
#define GBLK ((NN + 127) / 128)            // 782 gemm blocks (128 rows each)
#define FBLK (NN / 16)                     // 6250 fused pull blocks (16 nodes each)
#define PSZ 12500                          // dst-partition size (8 * 12500 = NN)
#define CSZ 50000                          // edge-chunk size (32 * 50000 = NE)
#define NCH 32                             // chunks
#define HBLK 256                           // hist blocks = 8 partitions * 32 chunks

using f32x4 = __attribute__((ext_vector_type(4))) float;
using bf16x8 = __attribute__((ext_vector_type(8))) short;  // 8 bf16 in 4 VGPRs
using u16 = unsigned short;
using u32 = unsigned int;
using u64 = unsigned long long;

__device__ inline u16 f2bf(float f) {
    unsigned u = __float_as_uint(f);
    unsigned r = (u + 0x7fffu + ((u >> 16) & 1u)) >> 16;  // RNE
    return (u16)r;
}
__device__ inline float bflo(unsigned u) { return __uint_as_float(u << 16); }
__device__ inline float bfhi(unsigned u) { return __uint_as_float(u & 0xffff0000u); }
__device__ inline float bf2f(u16 u) { return __uint_as_float((unsigned)u << 16); }
// packed fp32x2 -> bf16x2 (RNE); lowers to v_cvt_pk_bf16_f32 on gfx950
__device__ inline unsigned cvt2(float a, float b) {
    union { __hip_bfloat162 h; unsigned u; } c;
    c.h = __float22bfloat162_rn(make_float2(a, b));
    return c.u;
}

// ---------------- MFMA GEMM body, N=128, bf16 out (row stride 128) ----------------
template <typename AT, int KLIM, int KSTEPS, bool TAIL>
__device__ __forceinline__ void gemm_body(const AT* __restrict__ X,
                                          const short* __restrict__ Wp,
                                          u16* __restrict__ Out, int gblk) {
    const int lane = threadIdx.x & 63;
    const int wave = threadIdx.x >> 6;
    const int row0 = gblk * 128 + wave * 16;
    const int arow = row0 + (lane & 15);
    const int kgrp = (lane >> 4) << 3;
    const bool rvalid = arow < NN;
    const AT* aptr = X + (size_t)arow * KLIM + kgrp;
    const bf16x8* wp = reinterpret_cast<const bf16x8*>(Wp);

    f32x4 acc[8];
#pragma unroll
    for (int nt = 0; nt < 8; nt++) acc[nt] = (f32x4){0.f, 0.f, 0.f, 0.f};

    const int FULL = TAIL ? (KSTEPS - 1) : KSTEPS;
#pragma unroll 2
    for (int ks = 0; ks < FULL; ks++) {
        bf16x8 af;
        if (rvalid) {
            if constexpr (std::is_same_v<AT, float>) {
                // plain loads: X stays L3-allocatable (persists across replays)
                float4 f0 = *reinterpret_cast<const float4*>(aptr + ks * 32);
                float4 f1 = *reinterpret_cast<const float4*>(aptr + ks * 32 + 4);
                union { bf16x8 v; unsigned u[4]; } a;
                a.u[0] = cvt2(f0.x, f0.y);
                a.u[1] = cvt2(f0.z, f0.w);
                a.u[2] = cvt2(f1.x, f1.y);
                a.u[3] = cvt2(f1.z, f1.w);
                af = a.v;
            } else {
                af = *reinterpret_cast<const bf16x8*>(aptr + ks * 32);
            }
        } else {
#pragma unroll
            for (int j = 0; j < 8; j++) af[j] = 0;
        }
#pragma unroll
        for (int nt = 0; nt < 8; nt++) {
            bf16x8 bf = wp[(ks * 8 + nt) * 64 + lane];
            acc[nt] = __builtin_amdgcn_mfma_f32_16x16x32_bf16(af, bf, acc[nt], 0, 0, 0);
        }
    }
    if (TAIL) {
        const int ks = KSTEPS - 1;
        bf16x8 af;
#pragma unroll
        for (int j = 0; j < 8; j++) {
            int k = ks * 32 + kgrp + j;
            bool ok = rvalid && k < KLIM;
            if constexpr (std::is_same_v<AT, float>) {
                af[j] = (short)f2bf(ok ? aptr[ks * 32 + j] : 0.f);
            } else {
                af[j] = ok ? (short)aptr[ks * 32 + j] : (short)0;
            }
        }
#pragma unroll
        for (int nt = 0; nt < 8; nt++) {
            bf16x8 bf = wp[(ks * 8 + nt) * 64 + lane];
            acc[nt] = __builtin_amdgcn_mfma_f32_16x16x32_bf16(af, bf, acc[nt], 0, 0, 0);
        }
    }

    const int rbase = row0 + ((lane >> 4) << 2);
    const int cbase = lane & 15;
#pragma unroll
    for (int r = 0; r < 4; r++) {
        int orow = rbase + r;
        if (orow < NN) {
            u16* p = Out + (size_t)orow * 128 + cbase;
#pragma unroll
            for (int nt = 0; nt < 8; nt += 2) {
                unsigned v = cvt2(acc[nt][r], acc[nt + 1][r]);
                p[nt * 16] = (u16)v;
                p[nt * 16 + 16] = (u16)(v >> 16);
            }
        }
    }
}

// ---------------- K1: LDS-histogram count/rank (blocks < HBLK) + GEMM1 ----------------
// Block (p,c): LDS histogram of packed (count<<24 | fxsum(ea*2^15)) for dsts in
// partition p (12500 nodes, 50 KB) over edge chunk c (50000 edges).
// old>>24 = local rank within (c,d). counts[c][d] written with plain stores.
__global__ __launch_bounds__(512) void k_hist_gemm1(const float* __restrict__ X,
                                                    const short* __restrict__ Wp,
                                                    u16* __restrict__ Out,
                                                    const int* __restrict__ ei,
                                                    const float* __restrict__ ea,
                                                    u32* __restrict__ counts,
                                                    int* __restrict__ rank) {
    __shared__ u32 hist[PSZ];
    if (blockIdx.x < HBLK) {
        const int p = blockIdx.x >> 5;
        const int c = blockIdx.x & 31;
        const int dbase = p * PSZ;
        for (int i = threadIdx.x; i < PSZ; i += 512) hist[i] = 0;
        __syncthreads();
        const int ebeg = c * CSZ;
#pragma unroll 2
        for (int e = ebeg + (int)threadIdx.x; e < ebeg + CSZ; e += 512) {
            int d = ei[NE + e];
            unsigned rel = (unsigned)(d - dbase);
            if (rel < PSZ) {
                float w = ea[e];  // load only on partition hit (~1/8 of lanes)
                u32 add = (1u << 24) | (u32)(w * 32768.0f);
                u32 old = atomicAdd(&hist[rel], add);
                rank[e] = (int)(old >> 24);
            }
        }
        __syncthreads();
        for (int i = threadIdx.x; i < PSZ; i += 512)
            counts[(size_t)c * NN + dbase + i] = hist[i];
        return;
    }
    gemm_body<float, 500, 16, true>(X, Wp, Out, blockIdx.x - HBLK);
}

// ---------------- scan: fold 32 chunks per node (+cpfx, +dinv) ----------------
__global__ __launch_bounds__(256) void k_scan1(const u32* __restrict__ counts,
                                               u16* __restrict__ cpfx,
                                               int* __restrict__ row_ptr,
                                               int* __restrict__ part,
                                               float* __restrict__ dinv) {
    __shared__ int ts[256];
    const int tid = threadIdx.x;
    int base = blockIdx.x * SCAN_E + tid * 4;
    int v[4];
    int ssum = 0;
#pragma unroll
    for (int j = 0; j < 4; j++) {
        int d = base + j;
        if (d < NN) {
            u32 acc = 0;
#pragma unroll
            for (int c = 0; c < NCH; c++) {
                cpfx[(size_t)c * NN + d] = (u16)(acc >> 24);
                acc += counts[(size_t)c * NN + d];
            }
            v[j] = (int)(acc >> 24);
            dinv[d] = rsqrtf((float)(acc & 0xFFFFFFu) * (1.0f / 32768.0f) + 1.0f);
        } else {
            v[j] = 0;
        }
        ssum += v[j];
    }
    ts[tid] = ssum;
    __syncthreads();
    for (int o = 1; o < 256; o <<= 1) {
        int t = (tid >= o) ? ts[tid - o] : 0;
        __syncthreads();
        ts[tid] += t;
        __syncthreads();
    }
    int excl = ts[tid] - ssum;
#pragma unroll
    for (int j = 0; j < 4; j++) {
        if (base + j < NN) row_ptr[base + j] = excl;
        excl += v[j];
    }
    if (tid == 255) part[blockIdx.x] = ts[255];
}

__global__ void k_scan2(int* __restrict__ part) {
    if (threadIdx.x == 0) {
        int acc = 0;
        for (int b = 0; b < NBLK; b++) { int t = part[b]; part[b] = acc; acc += t; }
    }
}

__global__ __launch_bounds__(256) void k_scan3(int* __restrict__ row_ptr,
                                               const int* __restrict__ part) {
    int base = blockIdx.x * SCAN_E + threadIdx.x * 4;
    int off = part[blockIdx.x];
#pragma unroll
    for (int j = 0; j < 4; j++)
        if (base + j < NN) row_ptr[base + j] += off;
    if (blockIdx.x == 0 && threadIdx.x == 0) row_ptr[NN] = NE;
}

// ---------------- atomic-free scatter: pos = row_ptr[d] + cpfx[c][d] + rank[e] ----------------
__global__ __launch_bounds__(256) void k_scatter(const int* __restrict__ ei,
                                                 const float* __restrict__ ea,
                                                 const float* __restrict__ dinv,
                                                 const int* __restrict__ row_ptr,
                                                 const u16* __restrict__ cpfx,
                                                 const int* __restrict__ rank,
                                                 int2* __restrict__ csr) {
    int e = blockIdx.x * 256 + threadIdx.x;
    if (e >= NE) return;
    int s = ei[e], d = ei[NE + e];
    int c = e / CSZ;
    int pos = row_ptr[d] + (int)cpfx[(size_t)c * NN + d] + rank[e];
    float w = dinv[s] * ea[e] * dinv[d];
    csr[pos] = make_int2(s, __float_as_int(w));
}

// ---------------- single W-pack kernel (W1 | W2 | W3) ----------------
__device__ __forceinline__ void pack128(const float* __restrict__ W,
                                        short* __restrict__ Wp, int K, int t) {
    int lane = t & 63;
    int nt = (t >> 6) & 7;
    int ks = t >> 9;
    int col = nt * 16 + (lane & 15);
    int kb = ks * 32 + ((lane >> 4) << 3);
    bf16x8 v;
#pragma unroll
    for (int j = 0; j < 8; j++) {
        int k = kb + j;
        v[j] = (k < K) ? (short)f2bf(W[(size_t)k * 128 + col]) : (short)0;
    }
    reinterpret_cast<bf16x8*>(Wp)[t] = v;
}

__global__ __launch_bounds__(256) void k_packAll(const float* __restrict__ W1,
                                                 const float* __restrict__ W2,
                                                 const float* __restrict__ W3,
                                                 short* __restrict__ Wp1,
                                                 short* __restrict__ Wp2,
                                                 short* __restrict__ Wp3) {
    int t = blockIdx.x * 256 + threadIdx.x;
    if (t < 8192) {
        pack128(W1, Wp1, 500, t);
    } else if (t < 10240) {
        pack128(W2, Wp2, 128, t - 8192);
    } else if (t < 11008) {
        int tt = t - 10240;  // W3 [128][40] -> 3 n-tiles (48 cols, padded), 4 ksteps
        int lane = tt & 63;
        int nt = (tt >> 6) % 3;
        int ks = tt / 192;
        int col = nt * 16 + (lane & 15);
        int kb = ks * 32 + ((lane >> 4) << 3);
        bf16x8 v;
#pragma unroll
        for (int j = 0; j < 8; j++)
            v[j] = (col < 40) ? (short)f2bf(W3[(size_t)(kb + j) * 40 + col]) : (short)0;
        reinterpret_cast<bf16x8*>(Wp3)[tt] = v;
    }
}

// ---------------- fused CSR pull + dense transform ----------------
// 512 threads, 16 nodes/block (32 lanes/node). Phase 1: cooperative pull into
// LDS tile (padded). Phase 2: tile @ Wg via MFMA.
// MODE 1: h1 = relu(acc+b1) -> OutRow + tile@W2 -> OutG (8 n-tiles).
// MODE 2: h2 = relu(acc+b2)+R (LDS only); tile@W3 -> OutG stride-64 (3 n-tiles).
template <int MODE>
__global__ __launch_bounds__(512) void k_pull_fused(const u16* __restrict__ H,
                                                    const int* __restrict__ row_ptr,
                                                    const int2* __restrict__ csr,
                                                    const float* __restrict__ dinv,
                                                    const float* __restrict__ b,
                                                    const u16* __restrict__ R,
                                                    u16* __restrict__ OutRow,
                                                    const short* __restrict__ Wg,
                                                    u16* __restrict__ OutG) {
    __shared__ u16 tile[16][136];
    const int nl = threadIdx.x >> 5;          // 0..15 node-local
    const int node = blockIdx.x * 16 + nl;    // FBLK*16 == NN exactly
    const int cg = threadIdx.x & 31;
    const uint2* H2v = reinterpret_cast<const uint2*>(H);  // row stride 32

    float dv = dinv[node];
    float sw = dv * dv;  // self-loop weight
    uint2 h = H2v[node * 32 + cg];
    float4 acc;
    acc.x = bflo(h.x) * sw; acc.y = bfhi(h.x) * sw;
    acc.z = bflo(h.y) * sw; acc.w = bfhi(h.y) * sw;

    int e0 = row_ptr[node], e1 = row_ptr[node + 1];
    for (int base = e0; base < e1; base += 32) {
        int n = e1 - base;
        if (n > 32) n = 32;
        int2 sv = (cg < n) ? csr[base + cg] : make_int2(0, 0);
        int j = 0;
        for (; j + 4 <= n; j += 4) {
            int s0 = __shfl(sv.x, j + 0, 32);
            int s1 = __shfl(sv.x, j + 1, 32);
            int s2 = __shfl(sv.x, j + 2, 32);
            int s3 = __shfl(sv.x, j + 3, 32);
            float w0 = __int_as_float(__shfl(sv.y, j + 0, 32));
            float w1 = __int_as_float(__shfl(sv.y, j + 1, 32));
            float w2 = __int_as_float(__shfl(sv.y, j + 2, 32));
            float w3 = __int_as_float(__shfl(sv.y, j + 3, 32));
            uint2 g0 = H2v[s0 * 32 + cg];
            uint2 g1 = H2v[s1 * 32 + cg];
            uint2 g2 = H2v[s2 * 32 + cg];
            uint2 g3 = H2v[s3 * 32 + cg];
            acc.x = fmaf(w0, bflo(g0.x), acc.x); acc.y = fmaf(w0, bfhi(g0.x), acc.y);
            acc.z = fmaf(w0, bflo(g0.y), acc.z); acc.w = fmaf(w0, bfhi(g0.y), acc.w);
            acc.x = fmaf(w1, bflo(g1.x), acc.x); acc.y = fmaf(w1, bfhi(g1.x), acc.y);
            acc.z = fmaf(w1, bflo(g1.y), acc.z); acc.w = fmaf(w1, bfhi(g1.y), acc.w);
            acc.x = fmaf(w2, bflo(g2.x), acc.x); acc.y = fmaf(w2, bfhi(g2.x), acc.y);
            acc.z = fmaf(w2, bflo(g2.y), acc.z); acc.w = fmaf(w2, bfhi(g2.y), acc.w);
            acc.x = fmaf(w3, bflo(g3.x), acc.x); acc.y = fmaf(w3, bfhi(g3.x), acc.y);
            acc.z = fmaf(w3, bflo(g3.y), acc.z); acc.w = fmaf(w3, bfhi(g3.y), acc.w);
        }
        for (; j < n; j++) {
            int s = __shfl(sv.x, j, 32);
            float w = __int_as_float(__shfl(sv.y, j, 32));
            uint2 g = H2v[s * 32 + cg];
            acc.x = fmaf(w, bflo(g.x), acc.x); acc.y = fmaf(w, bfhi(g.x), acc.y);
            acc.z = fmaf(w, bflo(g.y), acc.z); acc.w = fmaf(w, bfhi(g.y), acc.w);
        }
    }

    float4 bb = reinterpret_cast<const float4*>(b)[cg];
    float4 o;
    o.x = fmaxf(acc.x + bb.x, 0.f);
    o.y = fmaxf(acc.y + bb.y, 0.f);
    o.z = fmaxf(acc.z + bb.z, 0.f);
    o.w = fmaxf(acc.w + bb.w, 0.f);
    if (MODE == 2) {
        uint2 r = reinterpret_cast<const uint2*>(R)[node * 32 + cg];
        o.x += bflo(r.x); o.y += bfhi(r.x);
        o.z += bflo(r.y); o.w += bfhi(r.y);
    }
    uint2 pk = make_uint2(cvt2(o.x, o.y), cvt2(o.z, o.w));
    *reinterpret_cast<uint2*>(&tile[nl][cg * 4]) = pk;
    if (MODE == 1)
        reinterpret_cast<uint2*>(OutRow)[node * 32 + cg] = pk;  // h1 for residual

    __syncthreads();

    // ---- gemm phase: tile(16x128) @ Wg ----
    const int lane = threadIdx.x & 63;
    const int wave = threadIdx.x >> 6;  // 0..7
    const int NT = (MODE == 1) ? 8 : 3;
    if (wave < NT) {
        const bf16x8* wp = reinterpret_cast<const bf16x8*>(Wg);
        f32x4 gacc = (f32x4){0.f, 0.f, 0.f, 0.f};
        const int arow = lane & 15;
        const int kg = (lane >> 4) << 3;
#pragma unroll
        for (int ks = 0; ks < 4; ks++) {
            bf16x8 af = *reinterpret_cast<const bf16x8*>(&tile[arow][ks * 32 + kg]);
            bf16x8 bf = wp[(ks * NT + wave) * 64 + lane];
            gacc = __builtin_amdgcn_mfma_f32_16x16x32_bf16(af, bf, gacc, 0, 0, 0);
        }
        const int rb = ((lane >> 4) << 2);
        const int cb = lane & 15;
        if (MODE == 1) {
            u16* p = OutG + (size_t)(blockIdx.x * 16 + rb) * 128 + wave * 16 + cb;
#pragma unroll
            for (int r = 0; r < 4; r++) p[(size_t)r * 128] = f2bf(gacc[r]);
        } else {
            int col = wave * 16 + cb;
            if (col < 40) {
                u16* p = OutG + (size_t)(blockIdx.x * 16 + rb) * 64 + col;
#pragma unroll
                for (int r = 0; r < 4; r++) p[(size_t)r * 64] = f2bf(gacc[r]);
            }
        }
    }
}

// ---------------- layer 3: pull(40ch, stride-64 bf16) + bias + log_softmax ----------------
__global__ __launch_bounds__(256) void k_pull40_lsm(const u16* __restrict__ G,
                                                    const int* __restrict__ row_ptr,
                                                    const int2* __restrict__ csr,
                                                    const float* __restrict__ dinv,
                                                    const float* __restrict__ b3,
                                                    float* __restrict__ out) {
    int node = blockIdx.x * 4 + (threadIdx.x >> 6);
    int lane = threadIdx.x & 63;
    const bool act = lane < 40;
    float dv = dinv[node];
    float sw = dv * dv;
    float acc = act ? bf2f(G[node * 64 + lane]) * sw : 0.f;

    int e0 = row_ptr[node], e1 = row_ptr[node + 1];
    for (int base = e0; base < e1; base += 64) {
        int n = e1 - base;
        if (n > 64) n = 64;
        int2 sv = (lane < n) ? csr[base + lane] : make_int2(0, 0);
        int j = 0;
        for (; j + 4 <= n; j += 4) {
            int s0 = __shfl(sv.x, j + 0);
            int s1 = __shfl(sv.x, j + 1);
            int s2 = __shfl(sv.x, j + 2);
            int s3 = __shfl(sv.x, j + 3);
            float w0 = __int_as_float(__shfl(sv.y, j + 0));
            float w1 = __int_as_float(__shfl(sv.y, j + 1));
            float w2 = __int_as_float(__shfl(sv.y, j + 2));
            float w3 = __int_as_float(__shfl(sv.y, j + 3));
            float g0 = act ? bf2f(G[s0 * 64 + lane]) : 0.f;
            float g1 = act ? bf2f(G[s1 * 64 + lane]) : 0.f;
            float g2 = act ? bf2f(G[s2 * 64 + lane]) : 0.f;
            float g3 = act ? bf2f(G[s3 * 64 + lane]) : 0.f;
            acc = fmaf(w0, g0, acc);
            acc = fmaf(w1, g1, acc);
            acc = fmaf(w2, g2, acc);
            acc = fmaf(w3, g3, acc);
        }
        for (; j < n; j++) {
            int s = __shfl(sv.x, j);
            float w = __int_as_float(__shfl(sv.y, j));
            float g = act ? bf2f(G[s * 64 + lane]) : 0.f;
            acc = fmaf(w, g, acc);
        }
    }

    float v = act ? acc + b3[lane] : -1e30f;
    float m = v;
    for (int o = 32; o; o >>= 1) m = fmaxf(m, __shfl_xor(m, o));
    float e = act ? expf(v - m) : 0.f;
    float ssum = e;
    for (int o = 32; o; o >>= 1) ssum += __shfl_xor(ssum, o);
    float ls = logf(ssum);
    if (act) out[node * 40 + lane] = v - m - ls;
}

// ---------------- launch ----------------
extern "C" void kernel_launch(void* const* d_in, const int* in_sizes, int n_in,
                              void* d_out, int out_size, void* d_ws, size_t ws_size,
                              hipStream_t stream) {
    const float* x  = (const float*)d_in[0];
    const int*   ei = (const int*)d_in[1];   // [2, NE] int32
    const float* ea = (const float*)d_in[2];
    const float* W1 = (const float*)d_in[3];
    const float* b1 = (const float*)d_in[4];
    const float* W2 = (const float*)d_in[5];
    const float* b2 = (const float*)d_in[6];
    const float* W3 = (const float*)d_in[7];
    const float* b3 = (const float*)d_in[8];
    float* out = (float*)d_out;

    // workspace carve-up (all regions 16 B aligned)
    short* Wp1     = (short*)d_ws;                    // 65536 bf16 (128 KB)
    short* Wp2     = Wp1 + 65536;                     // 16384 bf16 (32 KB)
    short* Wp3     = Wp2 + 16384;                     // 6144 bf16 (12 KB)
    u16*   Hb      = (u16*)(Wp3 + 6144);              // NN*128 bf16 (X@W1)
    u16*   h1b     = Hb + (size_t)NN * 128;           // NN*128 bf16 (h1)
    u16*   H2     = h1b + (size_t)NN * 128;           // NN*128 bf16 (h1@W2)
    u16*   G3b     = H2 + (size_t)NN * 128;           // NN*64 bf16 (padded rows)
    float* dinv    = (float*)(G3b + (size_t)NN * 64); // NN f32
    int*   row_ptr = (int*)(dinv + NN);               // NN+1 (pad 8)
    int*   part    = row_ptr + NN + 8;                // NBLK (pad 128)
    int*   rank    = part + 128;                      // NE i32
    u32*   counts  = (u32*)(rank + NE);               // 32*NN u32 (12.8 MB)
    u16*   cpfx    = (u16*)(counts + (size_t)NCH * NN); // 32*NN u16 (6.4 MB)
    int2*  csr     = (int2*)(cpfx + (size_t)NCH * NN); // NE int2

    // ---- W packing (single launch)
    k_packAll<<<43, 256, 0, stream>>>(W1, W2, W3, Wp1, Wp2, Wp3);

    // ---- K1: LDS-hist count/rank (256 blocks) || Hb = X @ W1 (782 blocks)
    k_hist_gemm1<<<HBLK + GBLK, 512, 0, stream>>>(x, Wp1, Hb, ei, ea, counts, rank);

    // ---- scan: fold chunks (+cpfx, +dinv), then row_ptr prefix
    k_scan1<<<NBLK, 256, 0, stream>>>(counts, cpfx, row_ptr, part, dinv);
    k_scan2<<<1, 64, 0, stream>>>(part);
    k_scan3<<<NBLK, 256, 0, stream>>>(row_ptr, part);

    // ---- atomic-free scatter
    k_scatter<<<(NE + 255) / 256, 256, 0, stream>>>(ei, ea, dinv, row_ptr, cpfx,
                                                    rank, csr);

    // ---- fused layer1-agg + layer2-lin: h1b = relu(pull(Hb)+b1); H2 = h1 @ W2
    k_pull_fused<1><<<FBLK, 512, 0, stream>>>(Hb, row_ptr, csr, dinv, b1, nullptr,
                                              h1b, Wp2, H2);

    // ---- fused layer2-agg + layer3-lin: h2 = relu(pull(H2)+b2)+h1 (LDS only);
    //      G3b = h2 @ W3 (stride-64)
    k_pull_fused<2><<<FBLK, 512, 0, stream>>>(H2, row_ptr, csr, dinv, b2, h1b,
                                              nullptr, Wp3, G3b);

    // ---- layer 3 agg + log_softmax
    k_pull40_lsm<<<NN / 4, 256, 0, stream>>>(G3b, row_ptr, csr, dinv, b3, out);
}